// Round 4
// baseline (80.088 us; speedup 1.0000x reference)
//
#include <hip/hip_runtime.h>

typedef __attribute__((ext_vector_type(4))) float f32x4;
typedef __attribute__((ext_vector_type(16))) float f32x16;
typedef __attribute__((ext_vector_type(8))) short s16x8;
typedef __attribute__((ext_vector_type(4))) short s16x4;
typedef __attribute__((ext_vector_type(4))) unsigned u32x4;

#define BATCH 4
#define SEQ 4096
#define EMB 1024
#define HD 64
#define QSCALE (0.125f * 1.44269504088896f)  // 1/sqrt(64) * log2(e)

// fp32 -> bf16 round-to-nearest-even
static __device__ __forceinline__ unsigned short f2bf(float f) {
  union { float f; unsigned int u; } a;
  a.f = f;
  unsigned int u = a.u;
  u += 0x7FFFu + ((u >> 16) & 1u);
  return (unsigned short)(u >> 16);
}

// raw v_exp_f32: 2^x
static __device__ __forceinline__ float fexp2(float x) {
  float r;
  asm("v_exp_f32 %0, %1\n\ts_nop 0" : "=v"(r) : "v"(x));
  return r;
}
// v_permlane32_swap_b32: a[32+i] <-> b[i]
static __device__ __forceinline__ void swap32f(float& a, float& b) {
  asm("s_nop 0\n\tv_permlane32_swap_b32 %0, %1\n\ts_nop 0" : "+v"(a), "+v"(b));
}
static __device__ __forceinline__ void swap32u(unsigned& a, unsigned& b) {
  asm("s_nop 0\n\tv_permlane32_swap_b32 %0, %1\n\ts_nop 0" : "+v"(a), "+v"(b));
}
static __device__ __forceinline__ unsigned cvtpk(float lo, float hi) {
  unsigned r;
  asm("v_cvt_pk_bf16_f32 %0, %1, %2" : "=v"(r) : "v"(lo), "v"(hi));
  return r;
}

// async global->LDS, 16B per lane (wave-uniform dst; HW adds lane*16)
#define GLL16(g, l)                                                        \
  __builtin_amdgcn_global_load_lds(                                        \
      (const __attribute__((address_space(1))) unsigned int*)(g),          \
      (__attribute__((address_space(3))) unsigned int*)(l), 16, 0, 0)

// ---------------------------------------------------------------------------
// Kernel 1: W [1024][64] fp32 (q,k,v) -> wT [192][1024] bf16 (row = out col)
// ---------------------------------------------------------------------------
__global__ __launch_bounds__(256) void k_wt(const float* __restrict__ Wq,
                                            const float* __restrict__ Wk,
                                            const float* __restrict__ Wv,
                                            unsigned short* __restrict__ wt) {
  __shared__ float lds[64][65];
  int tid = threadIdx.x;
  int which = blockIdx.x >> 4;  // 0=q 1=k 2=v
  int kt = blockIdx.x & 15;     // 64-row k tile
  const float* W = (which == 0) ? Wq : ((which == 1) ? Wk : Wv);
#pragma unroll
  for (int i = 0; i < 4; ++i) {
    int idx = i * 256 + tid;
    int row = idx >> 4, c4 = idx & 15;
    float4 v = *(const float4*)(W + (size_t)(kt * 64 + row) * 64 + c4 * 4);
    lds[row][c4 * 4 + 0] = v.x;
    lds[row][c4 * 4 + 1] = v.y;
    lds[row][c4 * 4 + 2] = v.z;
    lds[row][c4 * 4 + 3] = v.w;
  }
  __syncthreads();
#pragma unroll
  for (int i = 0; i < 2; ++i) {
    int idx = i * 256 + tid;
    int n = idx >> 3, kc = idx & 7;
    s16x8 v;
#pragma unroll
    for (int j = 0; j < 8; ++j) v[j] = (short)f2bf(lds[kc * 8 + j][n]);
    *(s16x8*)(wt + ((size_t)(which * 64 + n) * 1024 + kt * 64 + kc * 8)) = v;
  }
}

// ---------------------------------------------------------------------------
// Kernel 2: fused QKV projection, pipelined. x: direct global->reg->cvt_pk
// (no LDS round-trip). W: double-buffered GLL staging, 1 raw barrier + counted
// vmcnt per kt. Outputs Q/K/V in MFMA-fragment layouts (see k_attn).
// ---------------------------------------------------------------------------
__global__ __launch_bounds__(256) void k_proj(const float* __restrict__ x,
                                              const unsigned short* __restrict__ wt,
                                              const float* __restrict__ bq,
                                              const float* __restrict__ bk,
                                              const float* __restrict__ bv,
                                              unsigned short* __restrict__ qws,
                                              unsigned short* __restrict__ kws,
                                              unsigned short* __restrict__ vws) {
  __shared__ char wb[2][192 * 128];
  int tid = threadIdx.x;
  int w = tid >> 6, ln = tid & 63;
  int lg = ln >> 4, lc = ln & 15;
  int m0 = blockIdx.x * 64;
  const float* xp = x + (size_t)(m0 + w * 16 + lc) * 1024;

  f32x4 acc[12];
#pragma unroll
  for (int i = 0; i < 12; ++i) acc[i] = (f32x4){0.f, 0.f, 0.f, 0.f};

  f32x4 xr[4], xn[4];
#define XLOAD(kt_, dst_)                                                   \
  {                                                                        \
    dst_[0] = *(const f32x4*)(xp + (kt_)*64 + lg * 8);                     \
    dst_[1] = *(const f32x4*)(xp + (kt_)*64 + lg * 8 + 4);                 \
    dst_[2] = *(const f32x4*)(xp + (kt_)*64 + 32 + lg * 8);                \
    dst_[3] = *(const f32x4*)(xp + (kt_)*64 + 32 + lg * 8 + 4);            \
  }
#define WISSUE(kt_, buf_)                                                  \
  _Pragma("unroll") for (int p = 0; p < 6; ++p) {                          \
    int idx = p * 256 + tid;                                               \
    int rr = idx >> 3, cc = idx & 7;                                       \
    const char* src =                                                      \
        (const char*)wt + (size_t)rr * 2048 + (kt_)*128 + ((cc ^ (rr & 7)) << 4); \
    GLL16(src, wb[buf_] + (p * 256 + w * 64) * 16);                        \
  }

  XLOAD(0, xr);
  WISSUE(0, 0);

#pragma unroll 1
  for (int kt = 0; kt < 16; ++kt) {
    int cur = kt & 1;
    int ktn = kt < 15 ? kt + 1 : 15;
    XLOAD(ktn, xn);
    // drain x(kt) + wb(kt); leave the 4 xn loads in flight
    asm volatile("s_waitcnt vmcnt(4)" ::: "memory");
    __builtin_amdgcn_s_barrier();
    WISSUE(ktn, cur ^ 1);

    // convert x(kt) -> A fragments
    s16x8 a[2];
#pragma unroll
    for (int kk = 0; kk < 2; ++kk) {
      union { u32x4 u; s16x8 v; } c;
      c.u[0] = cvtpk(xr[kk * 2][0], xr[kk * 2][1]);
      c.u[1] = cvtpk(xr[kk * 2][2], xr[kk * 2][3]);
      c.u[2] = cvtpk(xr[kk * 2 + 1][0], xr[kk * 2 + 1][1]);
      c.u[3] = cvtpk(xr[kk * 2 + 1][2], xr[kk * 2 + 1][3]);
      a[kk] = c.v;
    }
    __builtin_amdgcn_s_setprio(1);
#pragma unroll
    for (int cf = 0; cf < 12; ++cf) {
#pragma unroll
      for (int kk = 0; kk < 2; ++kk) {
        int rowb = cf * 16 + lc;
        int ch = (kk * 4 + lg) ^ (rowb & 7);
        s16x8 bfr = *(const s16x8*)(wb[cur] + rowb * 128 + ch * 16);
        acc[cf] = __builtin_amdgcn_mfma_f32_16x16x32_bf16(a[kk], bfr, acc[cf], 0, 0, 0);
      }
    }
    __builtin_amdgcn_s_setprio(0);
#pragma unroll
    for (int i = 0; i < 4; ++i) xr[i] = xn[i];
  }
  asm volatile("s_waitcnt vmcnt(0)" ::: "memory");

  // epilogue: C layout col=lane&15, row=(lane>>4)*4+r
#pragma unroll
  for (int cf = 0; cf < 12; ++cf) {
    int dcol = (cf & 3) * 16 + lc;
    float bias = (cf < 4) ? bq[dcol] : ((cf < 8) ? bk[dcol] : bv[dcol]);
#pragma unroll
    for (int r = 0; r < 4; ++r) {
      int grow = m0 + w * 16 + lg * 4 + r;  // global row in [0,16384)
      int b = grow >> 12, t = grow & 4095;
      float val = acc[cf][r] + bias;
      if (cf < 4) {
        size_t off = (size_t)b * SEQ * 64 + (t >> 5) * 2048 + (dcol >> 4) * 512 +
                     ((dcol >> 3) & 1) * 256 + (t & 31) * 8 + (dcol & 7);
        qws[off] = f2bf(val * QSCALE);
      } else if (cf < 8) {
        size_t off = (size_t)b * SEQ * 64 + (t >> 5) * 2048 + (dcol >> 4) * 512 +
                     ((dcol >> 3) & 1) * 256 + (t & 31) * 8 + (dcol & 7);
        kws[off] = f2bf(val);
      } else {
        size_t off = (size_t)b * SEQ * 64 + (t >> 4) * 1024 + (dcol >> 5) * 512 +
                     ((t >> 3) & 1) * 256 + (dcol & 31) * 8 + (t & 7);
        vws[off] = f2bf(val);
      }
    }
  }
#undef XLOAD
#undef WISSUE
}

// ---------------------------------------------------------------------------
// Kernel 3: flash attention, 32x32 swapped-operand, LDS-free, barrier-free.
// Register-sequenced to fit 256 VGPR @ 2 waves/SIMD: QKT0 -> vf issue ->
// softmax0 -> QKT1 -> kf prefetch(t+1) -> softmax1 -> PV.
// ---------------------------------------------------------------------------
template <int NS>
__global__ __launch_bounds__(256, 2) void k_attn(const unsigned short* __restrict__ qf_g,
                                                 const unsigned short* __restrict__ kf_g,
                                                 const unsigned short* __restrict__ vf_g,
                                                 float* __restrict__ part,
                                                 float2* __restrict__ ml) {
  int tid = threadIdx.x;
  int w = tid >> 6, ln = tid & 63;
  // XCD swizzle: split == XCD id; 512KB K/V working set per XCD L2.
  int F = blockIdx.x;
  int chunk = 8 * NS;
  int idx = (F & 7) * chunk + (F >> 3);
  int split = idx >> 6;
  int rem = idx & 63;
  int b = rem >> 4, q16 = rem & 15;
  const int TPS = 64 / NS;
  int t0 = split * TPS;
  int tlast = t0 + TPS - 1;

  const unsigned short* qb = qf_g + (size_t)b * SEQ * 64;
  const unsigned short* kb = kf_g + (size_t)b * SEQ * 64;
  const unsigned short* vb = vf_g + (size_t)b * SEQ * 64;

  int qrow = q16 * 256 + w * 64;

  s16x8 qf[2][4];
#pragma unroll
  for (int sub = 0; sub < 2; ++sub)
#pragma unroll
    for (int db = 0; db < 4; ++db)
      qf[sub][db] = *(const s16x8*)(qb + (size_t)(((q16 * 8 + w * 2 + sub) * 4 + db) * 512 + ln * 8));

  f32x16 o_[2][2];
#pragma unroll
  for (int sub = 0; sub < 2; ++sub)
#pragma unroll
    for (int dt = 0; dt < 2; ++dt)
#pragma unroll
      for (int i = 0; i < 16; ++i) o_[sub][dt][i] = 0.f;
  float m_[2] = {-1e30f, -1e30f}, l_[2] = {0.f, 0.f};

  s16x8 kfc[2][4];
#pragma unroll
  for (int kt = 0; kt < 2; ++kt)
#pragma unroll
    for (int db = 0; db < 4; ++db)
      kfc[kt][db] = *(const s16x8*)(kb + (size_t)(((t0 * 2 + kt) * 4 + db) * 512 + ln * 8));

#pragma unroll 1
  for (int t = t0; t <= tlast; ++t) {
    // ---- QK^T sub0 (swapped): S^T[32k x 32q], col = lane&31 = q
    f32x16 s0[2];
    __builtin_amdgcn_s_setprio(1);
#pragma unroll
    for (int kt = 0; kt < 2; ++kt) {
      f32x16 a = {0.f, 0.f, 0.f, 0.f, 0.f, 0.f, 0.f, 0.f,
                  0.f, 0.f, 0.f, 0.f, 0.f, 0.f, 0.f, 0.f};
#pragma unroll
      for (int db = 0; db < 4; ++db)
        a = __builtin_amdgcn_mfma_f32_32x32x16_bf16(kfc[kt][db], qf[0][db], a, 0, 0, 0);
      s0[kt] = a;
    }
    __builtin_amdgcn_s_setprio(0);

    // ---- V fragments (latency hides under softmax0)
    s16x8 vf[4][2];
#pragma unroll
    for (int k4 = 0; k4 < 4; ++k4)
#pragma unroll
      for (int dt = 0; dt < 2; ++dt)
        vf[k4][dt] = *(const s16x8*)(vb + (size_t)(((t * 4 + k4) * 2 + dt) * 512 + ln * 8));

    s16x8 pf[2][4];
    // ---- softmax + pack, sub0 then (after QKT1) sub1
#define SOFTMAX_PACK(S_, SUBIDX)                                               \
    {                                                                          \
      float mx[16];                                                            \
      _Pragma("unroll") for (int i = 0; i < 16; ++i)                           \
          mx[i] = fmaxf(S_[0][i], S_[1][i]);                                   \
      _Pragma("unroll") for (int i = 0; i < 8; ++i) mx[i] = fmaxf(mx[i], mx[i + 8]); \
      _Pragma("unroll") for (int i = 0; i < 4; ++i) mx[i] = fmaxf(mx[i], mx[i + 4]); \
      float tm = fmaxf(fmaxf(mx[0], mx[1]), fmaxf(mx[2], mx[3]));              \
      float ta = tm, tb = tm;                                                  \
      swap32f(ta, tb);                                                         \
      tm = fmaxf(ta, tb);                                                      \
      if (!__all(tm <= m_[SUBIDX] + 8.0f)) {                                   \
        float mn = fmaxf(m_[SUBIDX], tm);                                      \
        float al = fexp2(m_[SUBIDX] - mn);                                     \
        _Pragma("unroll") for (int dt = 0; dt < 2; ++dt)                       \
            _Pragma("unroll") for (int i = 0; i < 16; ++i) o_[SUBIDX][dt][i] *= al; \
        l_[SUBIDX] *= al;                                                      \
        m_[SUBIDX] = mn;                                                       \
      }                                                                        \
      float mm = m_[SUBIDX];                                                   \
      _Pragma("unroll") for (int kt = 0; kt < 2; ++kt)                         \
          _Pragma("unroll") for (int i = 0; i < 16; ++i)                       \
              S_[kt][i] = fexp2(S_[kt][i] - mm);                               \
      float sm[16];                                                            \
      _Pragma("unroll") for (int i = 0; i < 16; ++i) sm[i] = S_[0][i] + S_[1][i]; \
      _Pragma("unroll") for (int i = 0; i < 8; ++i) sm[i] += sm[i + 8];        \
      _Pragma("unroll") for (int i = 0; i < 4; ++i) sm[i] += sm[i + 4];        \
      float ts = (sm[0] + sm[1]) + (sm[2] + sm[3]);                            \
      float sa = ts, sb = ts;                                                  \
      swap32f(sa, sb);                                                         \
      l_[SUBIDX] += sa + sb;                                                   \
      _Pragma("unroll") for (int k4 = 0; k4 < 4; ++k4) {                       \
        int kt = k4 >> 1, mr = 2 * (k4 & 1);                                   \
        unsigned a0 = cvtpk(S_[kt][mr * 4 + 0], S_[kt][mr * 4 + 1]);           \
        unsigned a1 = cvtpk(S_[kt][mr * 4 + 2], S_[kt][mr * 4 + 3]);           \
        unsigned b0 = cvtpk(S_[kt][mr * 4 + 4], S_[kt][mr * 4 + 5]);           \
        unsigned b1 = cvtpk(S_[kt][mr * 4 + 6], S_[kt][mr * 4 + 7]);           \
        swap32u(a0, b0);                                                       \
        swap32u(a1, b1);                                                       \
        union { u32x4 u; s16x8 v16; } cvt;                                     \
        cvt.u = (u32x4){a0, a1, b0, b1};                                       \
        pf[SUBIDX][k4] = cvt.v16;                                              \
      }                                                                        \
    }

    SOFTMAX_PACK(s0, 0)

    // ---- QK^T sub1 (kfc dies after this)
    f32x16 s1[2];
    __builtin_amdgcn_s_setprio(1);
#pragma unroll
    for (int kt = 0; kt < 2; ++kt) {
      f32x16 a = {0.f, 0.f, 0.f, 0.f, 0.f, 0.f, 0.f, 0.f,
                  0.f, 0.f, 0.f, 0.f, 0.f, 0.f, 0.f, 0.f};
#pragma unroll
      for (int db = 0; db < 4; ++db)
        a = __builtin_amdgcn_mfma_f32_32x32x16_bf16(kfc[kt][db], qf[1][db], a, 0, 0, 0);
      s1[kt] = a;
    }
    __builtin_amdgcn_s_setprio(0);

    // ---- prefetch K(t+1) (hides under softmax1 + PV)
    {
      int tn = t < tlast ? t + 1 : tlast;
#pragma unroll
      for (int kt = 0; kt < 2; ++kt)
#pragma unroll
        for (int db = 0; db < 4; ++db)
          kfc[kt][db] = *(const s16x8*)(kb + (size_t)(((tn * 2 + kt) * 4 + db) * 512 + ln * 8));
    }

    SOFTMAX_PACK(s1, 1)
#undef SOFTMAX_PACK

    // ---- PV (as O^T)
    __builtin_amdgcn_s_setprio(1);
#pragma unroll
    for (int sub = 0; sub < 2; ++sub)
#pragma unroll
      for (int dt = 0; dt < 2; ++dt)
#pragma unroll
        for (int k4 = 0; k4 < 4; ++k4)
          o_[sub][dt] = __builtin_amdgcn_mfma_f32_32x32x16_bf16(vf[k4][dt], pf[sub][k4],
                                                                o_[sub][dt], 0, 0, 0);
    __builtin_amdgcn_s_setprio(0);
  }

  // epilogue: part[(split*4+b)*64 + d][t] (coalesced)
  float* pb = part + (size_t)(split * 4 + b) * 64 * SEQ;
  int hi = ln >> 5, lq = ln & 31;
#pragma unroll
  for (int sub = 0; sub < 2; ++sub) {
    int tq = qrow + sub * 32 + lq;
#pragma unroll
    for (int dt = 0; dt < 2; ++dt)
#pragma unroll
      for (int re = 0; re < 16; ++re) {
        int d = dt * 32 + (re & 3) + 8 * (re >> 2) + 4 * hi;
        pb[(size_t)d * SEQ + tq] = o_[sub][dt][re];
      }
  }
  if (ln < 32) {
#pragma unroll
    for (int sub = 0; sub < 2; ++sub)
      ml[(size_t)(split * 4 + b) * SEQ + qrow + sub * 32 + ln] = make_float2(m_[sub], l_[sub]);
  }
}

// ---------------------------------------------------------------------------
// Kernel 4: combine KV-split partials (part layout [s][b][d][T], exp2 domain).
// ---------------------------------------------------------------------------
template <int NS>
__global__ __launch_bounds__(256) void k_red(const float* __restrict__ part,
                                             const float2* __restrict__ ml,
                                             float* __restrict__ out) {
  int tid = threadIdx.x;
  int tg = tid & 15, dg = tid >> 4;
  int R = blockIdx.x * 16 + tg;
  int b = R >> 12, t = R & 4095;
  float2 mls[NS];
#pragma unroll
  for (int s = 0; s < NS; ++s) mls[s] = ml[(size_t)(s * 4 + b) * SEQ + t];
  float M = mls[0].x;
#pragma unroll
  for (int s = 1; s < NS; ++s) M = fmaxf(M, mls[s].x);
  float Lden = 0.f;
#pragma unroll
  for (int s = 0; s < NS; ++s) Lden += mls[s].y * fexp2(mls[s].x - M);
  float acc[4] = {0.f, 0.f, 0.f, 0.f};
#pragma unroll
  for (int s = 0; s < NS; ++s) {
    float sc = fexp2(mls[s].x - M);
#pragma unroll
    for (int i = 0; i < 4; ++i)
      acc[i] += sc * part[((size_t)(s * 4 + b) * 64 + dg * 4 + i) * SEQ + t];
  }
  float inv = 1.0f / Lden;
  f32x4 o;
#pragma unroll
  for (int i = 0; i < 4; ++i) o[i] = acc[i] * inv;
  *(f32x4*)(out + (size_t)R * 64 + dg * 4) = o;
}

// ---------------------------------------------------------------------------
extern "C" void kernel_launch(void* const* d_in, const int* in_sizes, int n_in,
                              void* d_out, int out_size, void* d_ws, size_t ws_size,
                              hipStream_t stream) {
  const float* x = (const float*)d_in[0];
  const float* Wq = (const float*)d_in[1];
  const float* bq = (const float*)d_in[2];
  const float* Wk = (const float*)d_in[3];
  const float* bk = (const float*)d_in[4];
  const float* Wv = (const float*)d_in[5];
  const float* bv = (const float*)d_in[6];
  float* out = (float*)d_out;

  char* ws = (char*)d_ws;
  unsigned short* wt = (unsigned short*)(ws);             // 384 KB
  unsigned short* qws = (unsigned short*)(ws + 0x80000);  // 2 MB (qfrag)
  unsigned short* kws = (unsigned short*)(ws + 0x280000); // 2 MB (kfrag)
  unsigned short* vws = (unsigned short*)(ws + 0x480000); // 2 MB (vfrag)
  const size_t base = 0x680000;
  const size_t perSplit = (size_t)16384 * 64 * 4 + (size_t)16384 * 8;  // part + ml

  k_wt<<<48, 256, 0, stream>>>(Wq, Wk, Wv, wt);
  k_proj<<<256, 256, 0, stream>>>(x, wt, bq, bk, bv, qws, kws, vws);

#define RUN_NS(NSV)                                                           \
  {                                                                           \
    float* partp = (float*)(ws + base);                                       \
    float2* mlp = (float2*)(ws + base + (size_t)NSV * 16384 * 64 * 4);        \
    k_attn<NSV><<<64 * NSV, 256, 0, stream>>>(qws, kws, vws, partp, mlp);     \
    k_red<NSV><<<1024, 256, 0, stream>>>(partp, mlp, out);                    \
  }

  if (ws_size >= base + 8 * perSplit) {
    RUN_NS(8)
  } else if (ws_size >= base + 4 * perSplit) {
    RUN_NS(4)
  } else if (ws_size >= base + 2 * perSplit) {
    RUN_NS(2)
  } else {
    RUN_NS(1)
  }
#undef RUN_NS
}

// Round 5
// 75.420 us; speedup vs baseline: 1.0619x; 1.0619x over previous
//
#include <hip/hip_runtime.h>

typedef __attribute__((ext_vector_type(4))) float f32x4;
typedef __attribute__((ext_vector_type(16))) float f32x16;
typedef __attribute__((ext_vector_type(8))) short s16x8;
typedef __attribute__((ext_vector_type(4))) short s16x4;
typedef __attribute__((ext_vector_type(4))) unsigned u32x4;

#define BATCH 4
#define SEQ 4096
#define EMB 1024
#define HD 64
#define QSCALE (0.125f * 1.44269504088896f)  // 1/sqrt(64) * log2(e)

// fp32 -> bf16 round-to-nearest-even
static __device__ __forceinline__ unsigned short f2bf(float f) {
  union { float f; unsigned int u; } a;
  a.f = f;
  unsigned int u = a.u;
  u += 0x7FFFu + ((u >> 16) & 1u);
  return (unsigned short)(u >> 16);
}

// raw v_exp_f32: 2^x
static __device__ __forceinline__ float fexp2(float x) {
  float r;
  asm("v_exp_f32 %0, %1\n\ts_nop 0" : "=v"(r) : "v"(x));
  return r;
}
// v_permlane32_swap_b32: a[32+i] <-> b[i]
static __device__ __forceinline__ void swap32f(float& a, float& b) {
  asm("s_nop 0\n\tv_permlane32_swap_b32 %0, %1\n\ts_nop 0" : "+v"(a), "+v"(b));
}
static __device__ __forceinline__ void swap32u(unsigned& a, unsigned& b) {
  asm("s_nop 0\n\tv_permlane32_swap_b32 %0, %1\n\ts_nop 0" : "+v"(a), "+v"(b));
}
static __device__ __forceinline__ unsigned cvtpk(float lo, float hi) {
  unsigned r;
  asm("v_cvt_pk_bf16_f32 %0, %1, %2" : "=v"(r) : "v"(lo), "v"(hi));
  return r;
}

// ---------------------------------------------------------------------------
// Kernel 1: W [1024][64] fp32 (q,k,v) -> wt in MFMA B-fragment layout:
//   wt[(((kt*12 + cf)*2 + kk)*64 + lane)*8 + j]
//     = W^T[cf*16 + (lane&15)][kt*64 + kk*32 + (lane>>4)*8 + j]
// where cf = which*4 + cfl (q:0-3, k:4-7, v:8-11).
// ---------------------------------------------------------------------------
__global__ __launch_bounds__(256) void k_wt(const float* __restrict__ Wq,
                                            const float* __restrict__ Wk,
                                            const float* __restrict__ Wv,
                                            unsigned short* __restrict__ wt) {
  __shared__ float lds[64][65];
  int tid = threadIdx.x;
  int which = blockIdx.x >> 4;  // 0=q 1=k 2=v
  int kt = blockIdx.x & 15;     // 64-row k tile
  const float* W = (which == 0) ? Wq : ((which == 1) ? Wk : Wv);
#pragma unroll
  for (int i = 0; i < 4; ++i) {
    int idx = i * 256 + tid;
    int row = idx >> 4, c4 = idx & 15;
    float4 v = *(const float4*)(W + (size_t)(kt * 64 + row) * 64 + c4 * 4);
    lds[row][c4 * 4 + 0] = v.x;
    lds[row][c4 * 4 + 1] = v.y;
    lds[row][c4 * 4 + 2] = v.z;
    lds[row][c4 * 4 + 3] = v.w;
  }
  __syncthreads();
  // 512 fragment chunks (cfl 4 x kk 2 x lane 64), 2 per thread
#pragma unroll
  for (int i = 0; i < 2; ++i) {
    int c = i * 256 + tid;
    int cfl = c >> 7, kk = (c >> 6) & 1, l = c & 63;
    int lg = l >> 4, lc = l & 15;
    s16x8 v;
#pragma unroll
    for (int j = 0; j < 8; ++j) v[j] = (short)f2bf(lds[kk * 32 + lg * 8 + j][cfl * 16 + lc]);
    size_t off = ((((size_t)kt * 12 + (which * 4 + cfl)) * 2 + kk) * 64 + l) * 8;
    *(s16x8*)(wt + off) = v;
  }
}

// ---------------------------------------------------------------------------
// Kernel 2: fused QKV projection — barrier-free, LDS-free.
// Grid 256 x 4 waves. Wave (wr,wc): rows m0+wr*32..+31, cols cf = wc*6..+5.
// B-frags read straight from fragment-layout wt (L2-resident, coalesced).
// x per-lane -> cvt_pk -> A-frags. One-deep prefetch, manual 2x unroll.
// ---------------------------------------------------------------------------
__global__ __launch_bounds__(256, 1) void k_proj(const float* __restrict__ x,
                                                 const unsigned short* __restrict__ wt,
                                                 const float* __restrict__ bq,
                                                 const float* __restrict__ bk,
                                                 const float* __restrict__ bv,
                                                 unsigned short* __restrict__ qws,
                                                 unsigned short* __restrict__ kws,
                                                 unsigned short* __restrict__ vws) {
  int tid = threadIdx.x;
  int w = tid >> 6, ln = tid & 63;
  int lg = ln >> 4, lc = ln & 15;
  int wr = w & 1, wc = w >> 1;
  int m0 = blockIdx.x * 64;
  const float* xp = x + (size_t)(m0 + wr * 32 + lc) * 1024;  // +s*16 rows via +16384

  f32x4 acc[2][6];
#pragma unroll
  for (int s = 0; s < 2; ++s)
#pragma unroll
    for (int c = 0; c < 6; ++c) acc[s][c] = (f32x4){0.f, 0.f, 0.f, 0.f};

  f32x4 xA[2][2][2], xB[2][2][2];
  s16x8 bA[6][2], bB[6][2];

#define XL(dst_, kt_)                                                         \
  _Pragma("unroll") for (int s = 0; s < 2; ++s)                               \
      _Pragma("unroll") for (int kk = 0; kk < 2; ++kk) {                      \
    dst_[s][kk][0] = *(const f32x4*)(xp + s * 16384 + (kt_)*64 + kk * 32 + lg * 8); \
    dst_[s][kk][1] = *(const f32x4*)(xp + s * 16384 + (kt_)*64 + kk * 32 + lg * 8 + 4); \
  }
#define BL(dst_, kt_)                                                         \
  _Pragma("unroll") for (int c = 0; c < 6; ++c)                               \
      _Pragma("unroll") for (int kk = 0; kk < 2; ++kk)                        \
          dst_[c][kk] = *(const s16x8*)(wt + ((size_t)((kt_)*12 + wc * 6 + c) * 2 + kk) * 512 + ln * 8);
#define STEP(curx_, curb_, nx_, nb_, ktn_)                                    \
  {                                                                           \
    if ((ktn_) < 16) { XL(nx_, ktn_); BL(nb_, ktn_); }                        \
    s16x8 a[2][2];                                                            \
    _Pragma("unroll") for (int s = 0; s < 2; ++s)                             \
        _Pragma("unroll") for (int kk = 0; kk < 2; ++kk) {                    \
      union { u32x4 u; s16x8 v; } cv;                                         \
      cv.u[0] = cvtpk(curx_[s][kk][0][0], curx_[s][kk][0][1]);                \
      cv.u[1] = cvtpk(curx_[s][kk][0][2], curx_[s][kk][0][3]);                \
      cv.u[2] = cvtpk(curx_[s][kk][1][0], curx_[s][kk][1][1]);                \
      cv.u[3] = cvtpk(curx_[s][kk][1][2], curx_[s][kk][1][3]);                \
      a[s][kk] = cv.v;                                                        \
    }                                                                         \
    _Pragma("unroll") for (int s = 0; s < 2; ++s)                             \
        _Pragma("unroll") for (int c = 0; c < 6; ++c)                         \
            _Pragma("unroll") for (int kk = 0; kk < 2; ++kk)                  \
                acc[s][c] = __builtin_amdgcn_mfma_f32_16x16x32_bf16(          \
                    a[s][kk], curb_[c][kk], acc[s][c], 0, 0, 0);              \
  }

  XL(xA, 0);
  BL(bA, 0);
#pragma unroll 1
  for (int kt = 0; kt < 16; kt += 2) {
    STEP(xA, bA, xB, bB, kt + 1)
    STEP(xB, bB, xA, bA, kt + 2)
  }
#undef XL
#undef BL
#undef STEP

  // epilogue: C layout col=lane&15 (ncol), row=lg*4+r
#pragma unroll
  for (int cfl = 0; cfl < 6; ++cfl) {
    int cf = wc * 6 + cfl;
    int which = cf >> 2;
    int ncol = (cf & 3) * 16 + lc;
    float bias = (which == 0) ? bq[ncol] : ((which == 1) ? bk[ncol] : bv[ncol]);
#pragma unroll
    for (int s = 0; s < 2; ++s) {
#pragma unroll
      for (int r = 0; r < 4; ++r) {
        int grow = m0 + wr * 32 + s * 16 + lg * 4 + r;
        int b = grow >> 12, t = grow & 4095;
        float val = acc[s][cfl][r] + bias;
        if (which == 0) {
          size_t off = (size_t)b * SEQ * 64 + (t >> 5) * 2048 + (ncol >> 4) * 512 +
                       ((ncol >> 3) & 1) * 256 + (t & 31) * 8 + (ncol & 7);
          qws[off] = f2bf(val * QSCALE);
        } else if (which == 1) {
          size_t off = (size_t)b * SEQ * 64 + (t >> 5) * 2048 + (ncol >> 4) * 512 +
                       ((ncol >> 3) & 1) * 256 + (t & 31) * 8 + (ncol & 7);
          kws[off] = f2bf(val);
        } else {
          size_t off = (size_t)b * SEQ * 64 + (t >> 4) * 1024 + (ncol >> 5) * 512 +
                       ((t >> 3) & 1) * 256 + (ncol & 31) * 8 + (t & 7);
          vws[off] = f2bf(val);
        }
      }
    }
  }
}

// ---------------------------------------------------------------------------
// Kernel 3: flash attention, 32x32 swapped-operand, LDS-free, barrier-free.
// Sequenced: QKT0 -> vf issue -> softmax0 -> QKT1 -> kf prefetch -> softmax1
// -> PV. (unchanged from R4)
// ---------------------------------------------------------------------------
template <int NS>
__global__ __launch_bounds__(256, 2) void k_attn(const unsigned short* __restrict__ qf_g,
                                                 const unsigned short* __restrict__ kf_g,
                                                 const unsigned short* __restrict__ vf_g,
                                                 float* __restrict__ part,
                                                 float2* __restrict__ ml) {
  int tid = threadIdx.x;
  int w = tid >> 6, ln = tid & 63;
  int F = blockIdx.x;
  int chunk = 8 * NS;
  int idx = (F & 7) * chunk + (F >> 3);
  int split = idx >> 6;
  int rem = idx & 63;
  int b = rem >> 4, q16 = rem & 15;
  const int TPS = 64 / NS;
  int t0 = split * TPS;
  int tlast = t0 + TPS - 1;

  const unsigned short* qb = qf_g + (size_t)b * SEQ * 64;
  const unsigned short* kb = kf_g + (size_t)b * SEQ * 64;
  const unsigned short* vb = vf_g + (size_t)b * SEQ * 64;

  int qrow = q16 * 256 + w * 64;

  s16x8 qf[2][4];
#pragma unroll
  for (int sub = 0; sub < 2; ++sub)
#pragma unroll
    for (int db = 0; db < 4; ++db)
      qf[sub][db] = *(const s16x8*)(qb + (size_t)(((q16 * 8 + w * 2 + sub) * 4 + db) * 512 + ln * 8));

  f32x16 o_[2][2];
#pragma unroll
  for (int sub = 0; sub < 2; ++sub)
#pragma unroll
    for (int dt = 0; dt < 2; ++dt)
#pragma unroll
      for (int i = 0; i < 16; ++i) o_[sub][dt][i] = 0.f;
  float m_[2] = {-1e30f, -1e30f}, l_[2] = {0.f, 0.f};

  s16x8 kfc[2][4];
#pragma unroll
  for (int kt = 0; kt < 2; ++kt)
#pragma unroll
    for (int db = 0; db < 4; ++db)
      kfc[kt][db] = *(const s16x8*)(kb + (size_t)(((t0 * 2 + kt) * 4 + db) * 512 + ln * 8));

#pragma unroll 1
  for (int t = t0; t <= tlast; ++t) {
    f32x16 s0[2];
    __builtin_amdgcn_s_setprio(1);
#pragma unroll
    for (int kt = 0; kt < 2; ++kt) {
      f32x16 a = {0.f, 0.f, 0.f, 0.f, 0.f, 0.f, 0.f, 0.f,
                  0.f, 0.f, 0.f, 0.f, 0.f, 0.f, 0.f, 0.f};
#pragma unroll
      for (int db = 0; db < 4; ++db)
        a = __builtin_amdgcn_mfma_f32_32x32x16_bf16(kfc[kt][db], qf[0][db], a, 0, 0, 0);
      s0[kt] = a;
    }
    __builtin_amdgcn_s_setprio(0);

    s16x8 vf[4][2];
#pragma unroll
    for (int k4 = 0; k4 < 4; ++k4)
#pragma unroll
      for (int dt = 0; dt < 2; ++dt)
        vf[k4][dt] = *(const s16x8*)(vb + (size_t)(((t * 4 + k4) * 2 + dt) * 512 + ln * 8));

    s16x8 pf[2][4];
#define SOFTMAX_PACK(S_, SUBIDX)                                               \
    {                                                                          \
      float mx[16];                                                            \
      _Pragma("unroll") for (int i = 0; i < 16; ++i)                           \
          mx[i] = fmaxf(S_[0][i], S_[1][i]);                                   \
      _Pragma("unroll") for (int i = 0; i < 8; ++i) mx[i] = fmaxf(mx[i], mx[i + 8]); \
      _Pragma("unroll") for (int i = 0; i < 4; ++i) mx[i] = fmaxf(mx[i], mx[i + 4]); \
      float tm = fmaxf(fmaxf(mx[0], mx[1]), fmaxf(mx[2], mx[3]));              \
      float ta = tm, tb = tm;                                                  \
      swap32f(ta, tb);                                                         \
      tm = fmaxf(ta, tb);                                                      \
      if (!__all(tm <= m_[SUBIDX] + 8.0f)) {                                   \
        float mn = fmaxf(m_[SUBIDX], tm);                                      \
        float al = fexp2(m_[SUBIDX] - mn);                                     \
        _Pragma("unroll") for (int dt = 0; dt < 2; ++dt)                       \
            _Pragma("unroll") for (int i = 0; i < 16; ++i) o_[SUBIDX][dt][i] *= al; \
        l_[SUBIDX] *= al;                                                      \
        m_[SUBIDX] = mn;                                                       \
      }                                                                        \
      float mm = m_[SUBIDX];                                                   \
      _Pragma("unroll") for (int kt = 0; kt < 2; ++kt)                         \
          _Pragma("unroll") for (int i = 0; i < 16; ++i)                       \
              S_[kt][i] = fexp2(S_[kt][i] - mm);                               \
      float sm[16];                                                            \
      _Pragma("unroll") for (int i = 0; i < 16; ++i) sm[i] = S_[0][i] + S_[1][i]; \
      _Pragma("unroll") for (int i = 0; i < 8; ++i) sm[i] += sm[i + 8];        \
      _Pragma("unroll") for (int i = 0; i < 4; ++i) sm[i] += sm[i + 4];        \
      float ts = (sm[0] + sm[1]) + (sm[2] + sm[3]);                            \
      float sa = ts, sb = ts;                                                  \
      swap32f(sa, sb);                                                         \
      l_[SUBIDX] += sa + sb;                                                   \
      _Pragma("unroll") for (int k4 = 0; k4 < 4; ++k4) {                       \
        int kt = k4 >> 1, mr = 2 * (k4 & 1);                                   \
        unsigned a0 = cvtpk(S_[kt][mr * 4 + 0], S_[kt][mr * 4 + 1]);           \
        unsigned a1 = cvtpk(S_[kt][mr * 4 + 2], S_[kt][mr * 4 + 3]);           \
        unsigned b0 = cvtpk(S_[kt][mr * 4 + 4], S_[kt][mr * 4 + 5]);           \
        unsigned b1 = cvtpk(S_[kt][mr * 4 + 6], S_[kt][mr * 4 + 7]);           \
        swap32u(a0, b0);                                                       \
        swap32u(a1, b1);                                                       \
        union { u32x4 u; s16x8 v16; } cvt;                                     \
        cvt.u = (u32x4){a0, a1, b0, b1};                                       \
        pf[SUBIDX][k4] = cvt.v16;                                              \
      }                                                                        \
    }

    SOFTMAX_PACK(s0, 0)

    f32x16 s1[2];
    __builtin_amdgcn_s_setprio(1);
#pragma unroll
    for (int kt = 0; kt < 2; ++kt) {
      f32x16 a = {0.f, 0.f, 0.f, 0.f, 0.f, 0.f, 0.f, 0.f,
                  0.f, 0.f, 0.f, 0.f, 0.f, 0.f, 0.f, 0.f};
#pragma unroll
      for (int db = 0; db < 4; ++db)
        a = __builtin_amdgcn_mfma_f32_32x32x16_bf16(kfc[kt][db], qf[1][db], a, 0, 0, 0);
      s1[kt] = a;
    }
    __builtin_amdgcn_s_setprio(0);

    {
      int tn = t < tlast ? t + 1 : tlast;
#pragma unroll
      for (int kt = 0; kt < 2; ++kt)
#pragma unroll
        for (int db = 0; db < 4; ++db)
          kfc[kt][db] = *(const s16x8*)(kb + (size_t)(((tn * 2 + kt) * 4 + db) * 512 + ln * 8));
    }

    SOFTMAX_PACK(s1, 1)
#undef SOFTMAX_PACK

    __builtin_amdgcn_s_setprio(1);
#pragma unroll
    for (int sub = 0; sub < 2; ++sub)
#pragma unroll
      for (int dt = 0; dt < 2; ++dt)
#pragma unroll
        for (int k4 = 0; k4 < 4; ++k4)
          o_[sub][dt] = __builtin_amdgcn_mfma_f32_32x32x16_bf16(vf[k4][dt], pf[sub][k4],
                                                                o_[sub][dt], 0, 0, 0);
    __builtin_amdgcn_s_setprio(0);
  }

  float* pb = part + (size_t)(split * 4 + b) * 64 * SEQ;
  int hi = ln >> 5, lq = ln & 31;
#pragma unroll
  for (int sub = 0; sub < 2; ++sub) {
    int tq = qrow + sub * 32 + lq;
#pragma unroll
    for (int dt = 0; dt < 2; ++dt)
#pragma unroll
      for (int re = 0; re < 16; ++re) {
        int d = dt * 32 + (re & 3) + 8 * (re >> 2) + 4 * hi;
        pb[(size_t)d * SEQ + tq] = o_[sub][dt][re];
      }
  }
  if (ln < 32) {
#pragma unroll
    for (int sub = 0; sub < 2; ++sub)
      ml[(size_t)(split * 4 + b) * SEQ + qrow + sub * 32 + ln] = make_float2(m_[sub], l_[sub]);
  }
}

// ---------------------------------------------------------------------------
// Kernel 4: combine KV-split partials (part layout [s][b][d][T], exp2 domain).
// ---------------------------------------------------------------------------
template <int NS>
__global__ __launch_bounds__(256) void k_red(const float* __restrict__ part,
                                             const float2* __restrict__ ml,
                                             float* __restrict__ out) {
  int tid = threadIdx.x;
  int tg = tid & 15, dg = tid >> 4;
  int R = blockIdx.x * 16 + tg;
  int b = R >> 12, t = R & 4095;
  float2 mls[NS];
#pragma unroll
  for (int s = 0; s < NS; ++s) mls[s] = ml[(size_t)(s * 4 + b) * SEQ + t];
  float M = mls[0].x;
#pragma unroll
  for (int s = 1; s < NS; ++s) M = fmaxf(M, mls[s].x);
  float Lden = 0.f;
#pragma unroll
  for (int s = 0; s < NS; ++s) Lden += mls[s].y * fexp2(mls[s].x - M);
  float acc[4] = {0.f, 0.f, 0.f, 0.f};
#pragma unroll
  for (int s = 0; s < NS; ++s) {
    float sc = fexp2(mls[s].x - M);
#pragma unroll
    for (int i = 0; i < 4; ++i)
      acc[i] += sc * part[((size_t)(s * 4 + b) * 64 + dg * 4 + i) * SEQ + t];
  }
  float inv = 1.0f / Lden;
  f32x4 o;
#pragma unroll
  for (int i = 0; i < 4; ++i) o[i] = acc[i] * inv;
  *(f32x4*)(out + (size_t)R * 64 + dg * 4) = o;
}

// ---------------------------------------------------------------------------
extern "C" void kernel_launch(void* const* d_in, const int* in_sizes, int n_in,
                              void* d_out, int out_size, void* d_ws, size_t ws_size,
                              hipStream_t stream) {
  const float* x = (const float*)d_in[0];
  const float* Wq = (const float*)d_in[1];
  const float* bq = (const float*)d_in[2];
  const float* Wk = (const float*)d_in[3];
  const float* bk = (const float*)d_in[4];
  const float* Wv = (const float*)d_in[5];
  const float* bv = (const float*)d_in[6];
  float* out = (float*)d_out;

  char* ws = (char*)d_ws;
  unsigned short* wt = (unsigned short*)(ws);             // 384 KB (frag layout)
  unsigned short* qws = (unsigned short*)(ws + 0x80000);  // 2 MB (qfrag)
  unsigned short* kws = (unsigned short*)(ws + 0x280000); // 2 MB (kfrag)
  unsigned short* vws = (unsigned short*)(ws + 0x480000); // 2 MB (vfrag)
  const size_t base = 0x680000;
  const size_t perSplit = (size_t)16384 * 64 * 4 + (size_t)16384 * 8;  // part + ml

  k_wt<<<48, 256, 0, stream>>>(Wq, Wk, Wv, wt);
  k_proj<<<256, 256, 0, stream>>>(x, wt, bq, bk, bv, qws, kws, vws);

#define RUN_NS(NSV)                                                           \
  {                                                                           \
    float* partp = (float*)(ws + base);                                       \
    float2* mlp = (float2*)(ws + base + (size_t)NSV * 16384 * 64 * 4);        \
    k_attn<NSV><<<64 * NSV, 256, 0, stream>>>(qws, kws, vws, partp, mlp);     \
    k_red<NSV><<<1024, 256, 0, stream>>>(partp, mlp, out);                    \
  }

  if (ws_size >= base + 8 * perSplit) {
    RUN_NS(8)
  } else if (ws_size >= base + 4 * perSplit) {
    RUN_NS(4)
  } else if (ws_size >= base + 2 * perSplit) {
    RUN_NS(2)
  } else {
    RUN_NS(1)
  }
#undef RUN_NS
}